// Round 9
// baseline (1190.042 us; speedup 1.0000x reference)
//
#include <hip/hip_runtime.h>
#include <cmath>

#define B_  16
#define T_  2048
#define D_  512
#define TP_ 2049
#define KW_ 3

// ---------------- weight transform: wt[kw][i][o] = conv_w[o][i][kw] ----------------
__global__ void wtrans_kernel(const float* __restrict__ cw, float* __restrict__ wt) {
    int e = blockIdx.x * 256 + threadIdx.x;
    if (e >= KW_ * D_ * D_) return;
    int kw = e >> 18;            // D_*D_ = 2^18
    int r  = e & (D_ * D_ - 1);
    int i  = r >> 9;             // D_ = 2^9
    int o  = r & (D_ - 1);
    wt[e] = cw[(o * D_ + i) * KW_ + kw];
}

// ---------------- fused conv(k=3)+bias+relu+proj+sigmoid+mask+tail -> alphas ----------------
// Block 512 thr (8 waves), tile M=32 x N=512, K-step=8, 192 stages, dbuf LDS.
// Per-thread micro-tile 4x8 (32 acc) -> ~55 VGPR total: spill-free even if the
// allocator targets 8 waves/EU (64-VGPR budget), which round 3 showed it does.
#define FMA8(r, a)                              \
    acc[r][0] = fmaf(a, B0.x, acc[r][0]);       \
    acc[r][1] = fmaf(a, B0.y, acc[r][1]);       \
    acc[r][2] = fmaf(a, B0.z, acc[r][2]);       \
    acc[r][3] = fmaf(a, B0.w, acc[r][3]);       \
    acc[r][4] = fmaf(a, B1.x, acc[r][4]);       \
    acc[r][5] = fmaf(a, B1.y, acc[r][5]);       \
    acc[r][6] = fmaf(a, B1.z, acc[r][6]);       \
    acc[r][7] = fmaf(a, B1.w, acc[r][7]);

// B stage: 16 KB (8 k x 512 o) per stage; 512 threads x 16B x 2 issues.
// LDS dest must be wave-uniform base + lane*16 (m104); global src is per-lane.
#define ISSUE_B(sidx, buf)                                                      \
    {                                                                           \
        const float* gb = wt + ((size_t)(sidx) << 12) + (tid << 2);             \
        float* lb = &Bs[buf][0][0] + (wv << 8);                                 \
        __builtin_amdgcn_global_load_lds(                                       \
            (const __attribute__((address_space(1))) void*)(gb),                \
            (__attribute__((address_space(3))) void*)(lb), 16, 0, 0);           \
        __builtin_amdgcn_global_load_lds(                                       \
            (const __attribute__((address_space(1))) void*)(gb + 2048),         \
            (__attribute__((address_space(3))) void*)(lb + 2048), 16, 0, 0);    \
    }

#define LOAD_A(sidx)                                                            \
    if (tid < 256) {                                                            \
        const int koff = (sidx) >> 6;                                           \
        const int tr   = t0 + (tid & 31) - 1 + koff;                            \
        const int col  = (((sidx) & 63) << 3) + (tid >> 5);                     \
        a0r = ((unsigned)tr < (unsigned)T_) ? hb[((size_t)tr << 9) + col] : 0.f;\
    }

#define WRITE_A(buf) if (tid < 256) ((float*)As[buf])[tid] = a0r;

__launch_bounds__(512, 4)
__global__ void conv_alpha_kernel(const float* __restrict__ hidden,
                                  const float* __restrict__ wt,
                                  const float* __restrict__ conv_b,
                                  const float* __restrict__ out_w,
                                  const float* __restrict__ out_b,
                                  const float* __restrict__ mask,
                                  float* __restrict__ out_alphas) {
    __shared__ __align__(16) float As[2][8][32];    // [k][m] broadcast reads
    __shared__ __align__(16) float Bs[2][8][512];   // [k][o] float4 reads

    const int tid  = threadIdx.x;
    const int lane = tid & 63;
    const int wv   = tid >> 6;          // wave id 0..7
    const int mt4  = wv << 2;           // this wave's 4 output rows
    const int ln4  = lane << 2;

    const int m0 = blockIdx.x * 32;
    const int b  = m0 >> 11;            // / T_
    const int t0 = m0 & (T_ - 1);
    const float* hb = hidden + ((size_t)b << 20);   // b*T*D

    float acc[4][8];
#pragma unroll
    for (int i = 0; i < 4; ++i)
#pragma unroll
        for (int j = 0; j < 8; ++j) acc[i][j] = 0.f;

    float a0r;

    ISSUE_B(0, 0)
    LOAD_A(0)
    WRITE_A(0)

    const int NS = 192;                 // 3 kw * 64 i-chunks of 8
    for (int s = 0; s < NS; ++s) {
        const int cur = s & 1;
        __syncthreads();                // drains vmcnt (B arrival) + lgkm (A write)
        if (s + 1 < NS) { ISSUE_B(s + 1, cur ^ 1) LOAD_A(s + 1) }

#pragma unroll
        for (int k = 0; k < 8; ++k) {
            const float4 A0 = *(const float4*)&As[cur][k][mt4];
            const float4 B0 = *(const float4*)&Bs[cur][k][ln4];
            const float4 B1 = *(const float4*)&Bs[cur][k][ln4 + 256];
            FMA8(0, A0.x) FMA8(1, A0.y) FMA8(2, A0.z) FMA8(3, A0.w)
        }
        if (s + 1 < NS) WRITE_A(cur ^ 1)
    }

    // epilogue: relu(acc + conv_b) * out_w, reduce over all 512 o
    const float4 c0 = *(const float4*)(conv_b + ln4);
    const float4 c1 = *(const float4*)(conv_b + ln4 + 256);
    const float4 w0 = *(const float4*)(out_w + ln4);
    const float4 w1 = *(const float4*)(out_w + ln4 + 256);

    float s4[4];
#pragma unroll
    for (int ms = 0; ms < 4; ++ms) {
        float t;
        t  = fmaxf(acc[ms][0] + c0.x, 0.f) * w0.x;
        t += fmaxf(acc[ms][1] + c0.y, 0.f) * w0.y;
        t += fmaxf(acc[ms][2] + c0.z, 0.f) * w0.z;
        t += fmaxf(acc[ms][3] + c0.w, 0.f) * w0.w;
        t += fmaxf(acc[ms][4] + c1.x, 0.f) * w1.x;
        t += fmaxf(acc[ms][5] + c1.y, 0.f) * w1.y;
        t += fmaxf(acc[ms][6] + c1.z, 0.f) * w1.z;
        t += fmaxf(acc[ms][7] + c1.w, 0.f) * w1.w;
        s4[ms] = t;
    }
#pragma unroll
    for (int off = 1; off < 64; off <<= 1)
#pragma unroll
        for (int ms = 0; ms < 4; ++ms)
            s4[ms] += __shfl_xor(s4[ms], off, 64);

    if (lane == 0) {
        const float ob = out_b[0];
#pragma unroll
        for (int ms = 0; ms < 4; ++ms) {
            const int t = t0 + mt4 + ms;
            const float pre = s4[ms] + ob;
            float a = 1.f / (1.f + expf(-pre));
            a = fmaxf(a, 0.f);                            // SMOOTH=1, NOISE=0
            const float mcur  = mask[b * T_ + t];
            const float mprev = (t == 0) ? 1.f : mask[b * T_ + t - 1];
            out_alphas[b * TP_ + t] = a * mcur + 0.45f * (mprev - mcur);
        }
    }
}

// ---------------- sequential fp32 scan + fires + token_num ----------------
// Strict left-to-right fp32 order (validated; do not change order).
__launch_bounds__(64)
__global__ void scan_kernel(const float* __restrict__ mask,
                            float* __restrict__ alphas_io,
                            float* __restrict__ aps_ws,
                            float* __restrict__ out_fires,
                            float* __restrict__ out_tok) {
    const int b   = blockIdx.x;
    const int tid = threadIdx.x;
    __shared__ float aal[TP_];
    __shared__ float aps[TP_];

    for (int e = tid; e < T_; e += 64) aal[e] = alphas_io[b * TP_ + e];
    if (tid == 0) aal[T_] = 0.45f * mask[b * T_ + T_ - 1];
    __syncthreads();

    if (tid == 0) {
        float run = 0.f;
        for (int c = 0; c < T_; c += 32) {
            float r[32];
#pragma unroll
            for (int j = 0; j < 32; ++j) r[j] = aal[c + j];
#pragma unroll
            for (int j = 0; j < 32; ++j) { run += r[j]; aps[c + j] = run; }
        }
        run += aal[T_];
        aps[T_] = run;
        out_tok[b] = floorf(run);
        alphas_io[b * TP_ + T_] = aal[T_];
    }
    __syncthreads();

    for (int e = tid; e < TP_; e += 64) {
        const float p  = aps[e];
        const float pf = floorf(p);
        const float pv = (e == 0) ? 0.f : floorf(aps[e - 1]);
        const float fire = (pf - pv > 0.f) ? 1.f : 0.f;
        out_fires[b * TP_ + e] = fire + p - pf;
        aps_ws[b * TP_ + e] = p;
    }
}

// ---------------- CIF frames: integrate-and-fire over t ----------------
// grid = B_*8 blocks, 64 threads; block (b, dc) owns dims [dc*64, dc*64+64)
__launch_bounds__(64)
__global__ void cif_kernel(const float* __restrict__ hidden,
                           const float* __restrict__ mask,
                           const float* __restrict__ alphas,
                           const float* __restrict__ aps_ws,
                           float* __restrict__ out_emb,
                           int L) {
    const int b   = blockIdx.x >> 3;
    const int dc  = blockIdx.x & 7;
    const int tid = threadIdx.x;

    __shared__ float aal[TP_];
    __shared__ float aps[TP_];

    for (int e = tid; e < T_; e += 64) aal[e] = alphas[b * TP_ + e];
    if (tid == 0) aal[T_] = 0.45f * mask[b * T_ + T_ - 1];
    for (int e = tid; e < TP_; e += 64) aps[e] = aps_ws[b * TP_ + e];
    __syncthreads();

    const int d = dc * 64 + tid;
    const float* hp = hidden + ((size_t)b << 20) + d;
    float acc = 0.f;
    int   k   = 0;
    float prevf = 0.f;

    for (int t0 = 0; t0 < T_; t0 += 32) {
        float h[32];
#pragma unroll
        for (int j = 0; j < 32; ++j) h[j] = hp[(size_t)(t0 + j) << 9];
#pragma unroll
        for (int j = 0; j < 32; ++j) {
            const int t = t0 + j;
            const float p   = aps[t];
            const float pf  = floorf(p);
            const float a   = aal[t];
            const float rem = p - pf;
            const bool fire = (pf - prevf) > 0.f;
            if (fire) {
                if (k < L) out_emb[((size_t)b * L + k) * D_ + d] = acc + (a - rem) * h[j];
                acc = rem * h[j];
                ++k;
            } else {
                acc += a * h[j];
            }
            prevf = pf;
        }
    }
    // last step t = T_ (hidden row is zero)
    {
        const float p   = aps[T_];
        const float pf  = floorf(p);
        const bool fire = (pf - prevf) > 0.f;
        if (fire && k < L) out_emb[((size_t)b * L + k) * D_ + d] = acc;
    }
}

extern "C" void kernel_launch(void* const* d_in, const int* in_sizes, int n_in,
                              void* d_out, int out_size, void* d_ws, size_t ws_size,
                              hipStream_t stream) {
    const float* hidden = (const float*)d_in[0];
    const float* mask   = (const float*)d_in[1];
    const float* conv_w = (const float*)d_in[2];
    const float* conv_b = (const float*)d_in[3];
    const float* out_w  = (const float*)d_in[4];
    const float* out_b  = (const float*)d_in[5];

    // out layout: embeds[B,L,D] | token_num[B] | alphas[B,TP] | fires[B,TP]
    const int L = (out_size - B_ - 2 * B_ * TP_) / (B_ * D_);

    float* o_emb   = (float*)d_out;
    float* o_tok   = o_emb + (size_t)B_ * L * D_;
    float* o_alph  = o_tok + B_;
    float* o_fires = o_alph + (size_t)B_ * TP_;

    float* wt     = (float*)d_ws;                       // 3*512*512 floats = 3 MB
    float* aps_ws = wt + (size_t)KW_ * D_ * D_;         // B*TP floats = 131 KB

    if (L > 0)
        hipMemsetAsync(o_emb, 0, (size_t)B_ * L * D_ * sizeof(float), stream);

    wtrans_kernel<<<(KW_ * D_ * D_ + 255) / 256, 256, 0, stream>>>(conv_w, wt);
    conv_alpha_kernel<<<(B_ * T_) / 32, 512, 0, stream>>>(hidden, wt, conv_b, out_w, out_b,
                                                          mask, o_alph);
    scan_kernel<<<B_, 64, 0, stream>>>(mask, o_alph, aps_ws, o_fires, o_tok);
    cif_kernel<<<B_ * 8, 64, 0, stream>>>(hidden, mask, o_alph, aps_ws, o_emb, L);
}

// Round 12
// 1024.653 us; speedup vs baseline: 1.1614x; 1.1614x over previous
//
#include <hip/hip_runtime.h>
#include <cmath>

#define B_  16
#define T_  2048
#define D_  512
#define TP_ 2049
#define KW_ 3

// ---------------- weight transform: wt[kw][i][o] = conv_w[o][i][kw] ----------------
__global__ void wtrans_kernel(const float* __restrict__ cw, float* __restrict__ wt) {
    int e = blockIdx.x * 256 + threadIdx.x;
    if (e >= KW_ * D_ * D_) return;
    int kw = e >> 18;            // D_*D_ = 2^18
    int r  = e & (D_ * D_ - 1);
    int i  = r >> 9;             // D_ = 2^9
    int o  = r & (D_ - 1);
    wt[e] = cw[(o * D_ + i) * KW_ + kw];
}

// ---------------- fused conv(k=3)+bias+relu+proj+sigmoid+mask+tail -> alphas ----------------
// Block 512 thr (8 waves), tile M=16 x N=512, K-step=8, 192 stages, dbuf LDS.
// Wave w: rows (w>>1)*4..+3, cols (w&1)*256 + lane*4. Micro-tile 4x4 = 16 acc
// -> ~40 VGPR peak: 24 regs of headroom under the allocator's 64-VGPR budget
// (rounds 3/9 showed it picks 64 and spills marginal overflow). 33KB LDS ->
// 4 blocks/CU: 4 independent barrier domains hide each other's vmcnt drains.
#define FMA4(r, a)                              \
    acc[r][0] = fmaf(a, Bv.x, acc[r][0]);       \
    acc[r][1] = fmaf(a, Bv.y, acc[r][1]);       \
    acc[r][2] = fmaf(a, Bv.z, acc[r][2]);       \
    acc[r][3] = fmaf(a, Bv.w, acc[r][3]);

// B stage: 16 KB (8 k x 512 o); 512 threads x 16B x 2 issues.
// LDS dest is wave-uniform base + lane*16 (m104); global src is per-lane.
#define ISSUE_B(sidx, buf)                                                      \
    {                                                                           \
        const float* gb = wt + ((size_t)(sidx) << 12) + (tid << 2);             \
        float* lb = &Bs[buf][0][0] + (wv << 8);                                 \
        __builtin_amdgcn_global_load_lds(                                       \
            (const __attribute__((address_space(1))) void*)(gb),                \
            (__attribute__((address_space(3))) void*)(lb), 16, 0, 0);           \
        __builtin_amdgcn_global_load_lds(                                       \
            (const __attribute__((address_space(1))) void*)(gb + 2048),         \
            (__attribute__((address_space(3))) void*)(lb + 2048), 16, 0, 0);    \
    }

// A stage: 128 floats (8 k x 16 m); waves 0-1 only (tid<128 is wave-uniform).
#define LOAD_A(sidx)                                                            \
    if (tid < 128) {                                                            \
        const int koff = (sidx) >> 6;                                           \
        const int tr   = t0 + (tid & 15) - 1 + koff;                            \
        const int col  = (((sidx) & 63) << 3) + (tid >> 4);                     \
        a0r = ((unsigned)tr < (unsigned)T_) ? hb[((size_t)tr << 9) + col] : 0.f;\
    }

#define WRITE_A(buf) if (tid < 128) ((float*)As[buf])[tid] = a0r;

__launch_bounds__(512, 4)
__global__ void conv_alpha_kernel(const float* __restrict__ hidden,
                                  const float* __restrict__ wt,
                                  const float* __restrict__ conv_b,
                                  const float* __restrict__ out_w,
                                  const float* __restrict__ out_b,
                                  const float* __restrict__ mask,
                                  float* __restrict__ out_alphas) {
    __shared__ __align__(16) float As[2][8][16];    // [k][m] broadcast reads, 0.5KB/buf
    __shared__ __align__(16) float Bs[2][8][512];   // [k][o] float4 reads, 16KB/buf
    __shared__ float sred[8][4];

    const int tid  = threadIdx.x;
    const int wv   = tid >> 6;                  // wave id 0..7
    const int rg4  = (wv >> 1) << 2;            // row group base (0,4,8,12)
    const int col0 = ((wv & 1) << 8) + ((tid & 63) << 2);

    const int m0 = blockIdx.x << 4;             // *16
    const int b  = m0 >> 11;                    // / T_
    const int t0 = m0 & (T_ - 1);
    const float* hb = hidden + ((size_t)b << 20);   // b*T*D

    float acc[4][4];
#pragma unroll
    for (int i = 0; i < 4; ++i)
#pragma unroll
        for (int j = 0; j < 4; ++j) acc[i][j] = 0.f;

    float a0r;

    ISSUE_B(0, 0)
    LOAD_A(0)
    WRITE_A(0)

    const int NS = 192;                 // 3 kw * 64 i-chunks of 8
    for (int s = 0; s < NS; ++s) {
        const int cur = s & 1;
        __syncthreads();                // drains vmcnt (B arrival) + lgkm (A write)
        if (s + 1 < NS) { ISSUE_B(s + 1, cur ^ 1) LOAD_A(s + 1) }

#pragma unroll
        for (int k = 0; k < 8; ++k) {
            const float4 A0 = *(const float4*)&As[cur][k][rg4];
            const float4 Bv = *(const float4*)&Bs[cur][k][col0];
            FMA4(0, A0.x) FMA4(1, A0.y) FMA4(2, A0.z) FMA4(3, A0.w)
        }
        if (s + 1 < NS) WRITE_A(cur ^ 1)
    }

    // epilogue: relu(acc + conv_b) * out_w over this thread's 4 cols,
    // reduce across 64 lanes (256 cols), then combine wave pairs via LDS.
    const float4 cb = *(const float4*)(conv_b + col0);
    const float4 ow = *(const float4*)(out_w + col0);

    float s4[4];
#pragma unroll
    for (int r = 0; r < 4; ++r) {
        float t;
        t  = fmaxf(acc[r][0] + cb.x, 0.f) * ow.x;
        t += fmaxf(acc[r][1] + cb.y, 0.f) * ow.y;
        t += fmaxf(acc[r][2] + cb.z, 0.f) * ow.z;
        t += fmaxf(acc[r][3] + cb.w, 0.f) * ow.w;
        s4[r] = t;
    }
#pragma unroll
    for (int off = 1; off < 64; off <<= 1)
#pragma unroll
        for (int r = 0; r < 4; ++r)
            s4[r] += __shfl_xor(s4[r], off, 64);

    if ((tid & 63) == 0) {
#pragma unroll
        for (int r = 0; r < 4; ++r) sred[wv][r] = s4[r];
    }
    __syncthreads();

    if (tid < 16) {
        const int g = tid >> 2;                 // row group 0..3
        const int r = tid & 3;
        const int t = t0 + (g << 2) + r;
        const float pre = sred[2 * g][r] + sred[2 * g + 1][r] + out_b[0];
        float a = 1.f / (1.f + expf(-pre));
        a = fmaxf(a, 0.f);                      // SMOOTH=1, NOISE=0
        const float mcur  = mask[b * T_ + t];
        const float mprev = (t == 0) ? 1.f : mask[b * T_ + t - 1];
        out_alphas[b * TP_ + t] = a * mcur + 0.45f * (mprev - mcur);
    }
}

// ---------------- sequential fp32 scan + fires + token_num ----------------
// Strict left-to-right fp32 order (validated; do not change order).
__launch_bounds__(64)
__global__ void scan_kernel(const float* __restrict__ mask,
                            float* __restrict__ alphas_io,
                            float* __restrict__ aps_ws,
                            float* __restrict__ out_fires,
                            float* __restrict__ out_tok) {
    const int b   = blockIdx.x;
    const int tid = threadIdx.x;
    __shared__ float aal[TP_];
    __shared__ float aps[TP_];

    for (int e = tid; e < T_; e += 64) aal[e] = alphas_io[b * TP_ + e];
    if (tid == 0) aal[T_] = 0.45f * mask[b * T_ + T_ - 1];
    __syncthreads();

    if (tid == 0) {
        float run = 0.f;
        for (int c = 0; c < T_; c += 32) {
            float r[32];
#pragma unroll
            for (int j = 0; j < 32; ++j) r[j] = aal[c + j];
#pragma unroll
            for (int j = 0; j < 32; ++j) { run += r[j]; aps[c + j] = run; }
        }
        run += aal[T_];
        aps[T_] = run;
        out_tok[b] = floorf(run);
        alphas_io[b * TP_ + T_] = aal[T_];
    }
    __syncthreads();

    for (int e = tid; e < TP_; e += 64) {
        const float p  = aps[e];
        const float pf = floorf(p);
        const float pv = (e == 0) ? 0.f : floorf(aps[e - 1]);
        const float fire = (pf - pv > 0.f) ? 1.f : 0.f;
        out_fires[b * TP_ + e] = fire + p - pf;
        aps_ws[b * TP_ + e] = p;
    }
}

// ---------------- CIF frames: integrate-and-fire over t ----------------
// grid = B_*8 blocks, 64 threads; block (b, dc) owns dims [dc*64, dc*64+64)
__launch_bounds__(64)
__global__ void cif_kernel(const float* __restrict__ hidden,
                           const float* __restrict__ mask,
                           const float* __restrict__ alphas,
                           const float* __restrict__ aps_ws,
                           float* __restrict__ out_emb,
                           int L) {
    const int b   = blockIdx.x >> 3;
    const int dc  = blockIdx.x & 7;
    const int tid = threadIdx.x;

    __shared__ float aal[TP_];
    __shared__ float aps[TP_];

    for (int e = tid; e < T_; e += 64) aal[e] = alphas[b * TP_ + e];
    if (tid == 0) aal[T_] = 0.45f * mask[b * T_ + T_ - 1];
    for (int e = tid; e < TP_; e += 64) aps[e] = aps_ws[b * TP_ + e];
    __syncthreads();

    const int d = dc * 64 + tid;
    const float* hp = hidden + ((size_t)b << 20) + d;
    float acc = 0.f;
    int   k   = 0;
    float prevf = 0.f;

    for (int t0 = 0; t0 < T_; t0 += 32) {
        float h[32];
#pragma unroll
        for (int j = 0; j < 32; ++j) h[j] = hp[(size_t)(t0 + j) << 9];
#pragma unroll
        for (int j = 0; j < 32; ++j) {
            const int t = t0 + j;
            const float p   = aps[t];
            const float pf  = floorf(p);
            const float a   = aal[t];
            const float rem = p - pf;
            const bool fire = (pf - prevf) > 0.f;
            if (fire) {
                if (k < L) out_emb[((size_t)b * L + k) * D_ + d] = acc + (a - rem) * h[j];
                acc = rem * h[j];
                ++k;
            } else {
                acc += a * h[j];
            }
            prevf = pf;
        }
    }
    // last step t = T_ (hidden row is zero)
    {
        const float p   = aps[T_];
        const float pf  = floorf(p);
        const bool fire = (pf - prevf) > 0.f;
        if (fire && k < L) out_emb[((size_t)b * L + k) * D_ + d] = acc;
    }
}

extern "C" void kernel_launch(void* const* d_in, const int* in_sizes, int n_in,
                              void* d_out, int out_size, void* d_ws, size_t ws_size,
                              hipStream_t stream) {
    const float* hidden = (const float*)d_in[0];
    const float* mask   = (const float*)d_in[1];
    const float* conv_w = (const float*)d_in[2];
    const float* conv_b = (const float*)d_in[3];
    const float* out_w  = (const float*)d_in[4];
    const float* out_b  = (const float*)d_in[5];

    // out layout: embeds[B,L,D] | token_num[B] | alphas[B,TP] | fires[B,TP]
    const int L = (out_size - B_ - 2 * B_ * TP_) / (B_ * D_);

    float* o_emb   = (float*)d_out;
    float* o_tok   = o_emb + (size_t)B_ * L * D_;
    float* o_alph  = o_tok + B_;
    float* o_fires = o_alph + (size_t)B_ * TP_;

    float* wt     = (float*)d_ws;                       // 3*512*512 floats = 3 MB
    float* aps_ws = wt + (size_t)KW_ * D_ * D_;         // B*TP floats = 131 KB

    if (L > 0)
        hipMemsetAsync(o_emb, 0, (size_t)B_ * L * D_ * sizeof(float), stream);

    wtrans_kernel<<<(KW_ * D_ * D_ + 255) / 256, 256, 0, stream>>>(conv_w, wt);
    conv_alpha_kernel<<<(B_ * T_) / 16, 512, 0, stream>>>(hidden, wt, conv_b, out_w, out_b,
                                                          mask, o_alph);
    scan_kernel<<<B_, 64, 0, stream>>>(mask, o_alph, aps_ws, o_fires, o_tok);
    cif_kernel<<<B_ * 8, 64, 0, stream>>>(hidden, mask, o_alph, aps_ws, o_emb, L);
}